// Round 8
// baseline (4851.686 us; speedup 1.0000x reference)
//
#include <hip/hip_runtime.h>
#include <hip/hip_bf16.h>

// ============================================================================
// Bidirectional 2-layer GRU encoder (Keras reset_after=True), MI355X/gfx950.
// Numerics: split-bf16 (hi+lo, 3-product MFMA) everywhere (absmax 3.9e-3).
// Round 8: slice-pipelined scan. 12 waves: 0-5 MFMA, 6-7 gates-only,
// 8-11 free-running loaders (no barriers) that poll per-slice producer flags
// and stage h slices into parity-double-buffered LDS as they arrive.
// Waves 0-7 sync via a monotonic LDS barrier (sync8). Producer protocol
// (sc1 relaxed stores + vmcnt drain + relaxed agent flag) unchanged.
// ============================================================================

typedef __attribute__((ext_vector_type(8))) short short8;
typedef __attribute__((ext_vector_type(8))) __bf16 bf16x8;
typedef __attribute__((ext_vector_type(4))) float f32x4;
typedef __attribute__((ext_vector_type(4))) int i32x4;
typedef __attribute__((ext_vector_type(2))) float f32x2;

#define DEVINLINE __device__ __forceinline__

static constexpr int B = 32, T = 256, U = 512, NG = 1536;
static constexpr int BU = B * U;             // 16384
static constexpr long OUT_ELEMS = 8388608;   // 32*256*1024
static constexpr float SCALE_BN = 0.9995003746879552f;  // 1/sqrt(1+1e-3)
static constexpr int HSTR = 520;             // LDS row stride (shorts), 1040B

DEVINLINE unsigned bfbits(float f) {
  unsigned u = __float_as_uint(f);
  return (u + 0x7fffu + ((u >> 16) & 1u)) >> 16;
}
DEVINLINE float bf2f(unsigned bits) { return __uint_as_float(bits << 16); }
DEVINLINE void split2(float v, unsigned& hi, unsigned& lo) {
  hi = bfbits(v);
  lo = bfbits(v - bf2f(hi));
}
DEVINLINE float sigmoidf_(float x) { return 1.f / (1.f + __expf(-x)); }
DEVINLINE float tanhf_(float x) {
  x = fminf(15.f, fmaxf(-15.f, x));
  float e = __expf(2.f * x);
  return (e - 1.f) / (e + 1.f);
}
DEVINLINE f32x4 mfma16(short8 a, short8 b, f32x4 c) {
  return __builtin_amdgcn_mfma_f32_16x16x32_bf16(
      __builtin_bit_cast(bf16x8, a), __builtin_bit_cast(bf16x8, b), c, 0, 0, 0);
}

// ---------------------------------------------------------------------------
// Weight transpose + f32->bf16 hi/lo:  in [K][N] f32 -> oh/ol [N][K] bf16
// ---------------------------------------------------------------------------
__global__ __launch_bounds__(256)
void transpose_w(const float* __restrict__ in, unsigned short* __restrict__ oh,
                 unsigned short* __restrict__ ol, int K, int N) {
  __shared__ float tile[32][33];
  const int n0 = blockIdx.x * 32, k0 = blockIdx.y * 32;
  const int tx = threadIdx.x & 31, ty = threadIdx.x >> 5;
  for (int i = ty; i < 32; i += 8)
    tile[i][tx] = in[(long)(k0 + i) * N + n0 + tx];
  __syncthreads();
  for (int i = ty; i < 32; i += 8) {
    const float v = tile[tx][i];
    unsigned hi, lo;
    split2(v, hi, lo);
    oh[(long)(n0 + i) * K + k0 + tx] = (unsigned short)hi;
    ol[(long)(n0 + i) * K + k0 + tx] = (unsigned short)lo;
  }
}

// ---------------------------------------------------------------------------
// Embedding: x0{h,l}[r=t*32+b][0..511] = split(E[x[b][t]][:])
// ---------------------------------------------------------------------------
__global__ __launch_bounds__(256)
void embed_kernel(const int* __restrict__ x, const float* __restrict__ E,
                  unsigned short* __restrict__ xh, unsigned short* __restrict__ xl) {
  const int r = blockIdx.x;
  const int t = r >> 5, b = r & 31;
  const int id = x[b * T + t];
  const float* src = E + (long)id * 512;
  f32x2 v = *reinterpret_cast<const f32x2*>(src + threadIdx.x * 2);
  unsigned h0, l0, h1, l1;
  split2(v.x, h0, l0);
  split2(v.y, h1, l1);
  ((unsigned*)xh)[(long)r * 256 + threadIdx.x] = h0 | (h1 << 16);
  ((unsigned*)xl)[(long)r * 256 + threadIdx.x] = l0 | (l1 << 16);
}

// ---------------------------------------------------------------------------
// GEMM: C[M=8192][1536] f32 = A[M][K] @ Bt[1536][K]^T + bias (hi+lo 3-prod)
// ---------------------------------------------------------------------------
template <int K>
__global__ __launch_bounds__(256)
void gemm_bias(const unsigned short* __restrict__ Ah,
               const unsigned short* __restrict__ Al,
               const unsigned short* __restrict__ Bh,
               const unsigned short* __restrict__ Bl,
               const float* __restrict__ bias, float* __restrict__ C) {
  __shared__ __align__(16) unsigned short AsH[128 * 32];
  __shared__ __align__(16) unsigned short BsH[128 * 32];
  __shared__ __align__(16) unsigned short AsL[128 * 32];
  __shared__ __align__(16) unsigned short BsL[128 * 32];
  const int m0 = blockIdx.x * 128, n0 = blockIdx.y * 128;
  const int tid = threadIdx.x, lane = tid & 63, wave = tid >> 6;
  const int wr = wave >> 1, wc = wave & 1, lr = lane & 15, kq = lane >> 4;
  f32x4 acc[4][4] = {};
  for (int kt = 0; kt < K / 32; ++kt) {
    const int k0 = kt * 32;
    i32x4 vah[2], vbh[2], val[2], vbl[2];
#pragma unroll
    for (int u = 0; u < 2; ++u) {
      const int idx = tid + u * 256, row = idx >> 2, sub = idx & 3;
      vah[u] = *reinterpret_cast<const i32x4*>(Ah + (long)(m0 + row) * K + k0 + sub * 8);
      vbh[u] = *reinterpret_cast<const i32x4*>(Bh + (long)(n0 + row) * K + k0 + sub * 8);
      val[u] = *reinterpret_cast<const i32x4*>(Al + (long)(m0 + row) * K + k0 + sub * 8);
      vbl[u] = *reinterpret_cast<const i32x4*>(Bl + (long)(n0 + row) * K + k0 + sub * 8);
    }
    __syncthreads();
#pragma unroll
    for (int u = 0; u < 2; ++u) {
      const int idx = tid + u * 256;
      *reinterpret_cast<i32x4*>(AsH + idx * 8) = vah[u];
      *reinterpret_cast<i32x4*>(BsH + idx * 8) = vbh[u];
      *reinterpret_cast<i32x4*>(AsL + idx * 8) = val[u];
      *reinterpret_cast<i32x4*>(BsL + idx * 8) = vbl[u];
    }
    __syncthreads();
    short8 afh[4], bfh[4], afl[4], bfl[4];
#pragma unroll
    for (int i = 0; i < 4; ++i) {
      afh[i] = *reinterpret_cast<const short8*>(AsH + (wr * 64 + i * 16 + lr) * 32 + kq * 8);
      bfh[i] = *reinterpret_cast<const short8*>(BsH + (wc * 64 + i * 16 + lr) * 32 + kq * 8);
      afl[i] = *reinterpret_cast<const short8*>(AsL + (wr * 64 + i * 16 + lr) * 32 + kq * 8);
      bfl[i] = *reinterpret_cast<const short8*>(BsL + (wc * 64 + i * 16 + lr) * 32 + kq * 8);
    }
#pragma unroll
    for (int i = 0; i < 4; ++i)
#pragma unroll
      for (int j = 0; j < 4; ++j) {
        acc[i][j] = mfma16(afh[i], bfh[j], acc[i][j]);
        acc[i][j] = mfma16(afh[i], bfl[j], acc[i][j]);
        acc[i][j] = mfma16(afl[i], bfh[j], acc[i][j]);
      }
  }
#pragma unroll
  for (int j = 0; j < 4; ++j) {
    const int col = n0 + wc * 64 + j * 16 + lr;
    const float bv = bias[col];
#pragma unroll
    for (int i = 0; i < 4; ++i) {
      const int row0 = m0 + wr * 64 + i * 16 + kq * 4;
#pragma unroll
      for (int r = 0; r < 4; ++r)
        C[(long)(row0 + r) * NG + col] = acc[i][j][r] + bv;
    }
  }
}

// ---------------------------------------------------------------------------
// Monotonic LDS barrier for waves 0-7 (loaders excluded).
// ---------------------------------------------------------------------------
DEVINLINE void sync8(int* cnt, int target) {
  if ((threadIdx.x & 63) == 0)
    __hip_atomic_fetch_add(cnt, 1, __ATOMIC_RELEASE, __HIP_MEMORY_SCOPE_WORKGROUP);
  while (__hip_atomic_load(cnt, __ATOMIC_ACQUIRE, __HIP_MEMORY_SCOPE_WORKGROUP) < target) {
  }
}

// ---------------------------------------------------------------------------
// Persistent GRU scan, slice-pipelined.
// Grid = 32 blocks: dir = bid>>4, wg = bid&15 owns hidden units [wg*32, +32).
// 768 threads = 12 waves:
//   waves 0-5: MFMA (wave = (g=w>>1 gate, half=w&1 unit-16), Wh hi+lo in regs)
//   waves 6-7: gates only (tasks tid<512 cover all waves 0-7)
//   waves 8-11: FREE-RUNNING loaders, 4 slices each (j%4 == w-8); poll the
//     slice's producer flag, load 4KB (hi+lo) via relaxed agent atomics,
//     write LDS h[par], bump ld_ready[j]=s+1 (release).
// Skew proof: any WG reaching step s+2 requires all flags>=s+1, i.e. this WG
// finished step s => parity-double LDS (h[par]) never overwritten while read.
// ---------------------------------------------------------------------------
__global__ __launch_bounds__(768, 1)
void gru_scan(const float* __restrict__ xgf, const float* __restrict__ xgb,
              const unsigned short* __restrict__ whtfh,
              const unsigned short* __restrict__ whtfl,
              const unsigned short* __restrict__ whtbh,
              const unsigned short* __restrict__ whtbl,
              const float* __restrict__ rbf, const float* __restrict__ rbb,
              const float* __restrict__ h0L,    // [2][B][U] this layer, f32
              unsigned short* __restrict__ hbh, // [2 dir][2 par][BU] bf16 hi
              unsigned short* __restrict__ hbl, // [2 dir][2 par][BU] bf16 lo
              int* __restrict__ flags,          // [2 dirs][16]
              unsigned short* __restrict__ out0h,
              unsigned short* __restrict__ out0l,
              float* __restrict__ outF,
              float* __restrict__ hT,
              const int layer) {
  const int dir = blockIdx.x >> 4, wg = blockIdx.x & 15;
  const int j0 = wg * 32;
  const int tid = threadIdx.x, wave = tid >> 6, lane = tid & 63;
  const int lr = lane & 15, kq = lane >> 4;
  const float* xg = dir ? xgb : xgf;
  const unsigned short* wth = dir ? whtbh : whtfh;
  const unsigned short* wtl = dir ? whtbl : whtfl;
  const float* rb = dir ? rbb : rbf;
  const float* h0d = h0L + dir * BU;
  unsigned short* hbhd = hbh + dir * 2 * BU;
  unsigned short* hbld = hbl + dir * 2 * BU;
  int* flg = flags + dir * 16;

  // LDS: h double-buffered by step parity; [par][plane hi/lo][b][HSTR]
  __shared__ __align__(16) unsigned short h_lds[2][2][32][HSTR];  // 133,120 B
  __shared__ float rg_lds[32][97];                                // 12,416 B
  __shared__ int ld_ready[16];
  __shared__ int s8cnt[2];

  if (tid < 16) ld_ready[tid] = 0;
  if (tid < 2) s8cnt[tid] = 0;
  __syncthreads();  // only barrier executed by all 12 waves

  // ======================= LOADER ROLE (waves 8-11) ========================
  if (wave >= 8) {
    const int lw = wave - 8;
    for (int s = 0; s < T; ++s) {
      const int par = s & 1;
      const unsigned short* hsh = hbhd + par * BU;
      const unsigned short* hsl = hbld + par * BU;
#pragma unroll
      for (int idx = 0; idx < 4; ++idx) {
        const int j = lw + idx * 4;
        if (s == 0) {
#pragma unroll
          for (int i = 0; i < 4; ++i) {
            const int c = i * 64 + lane, b = c >> 3, ch = (c & 7) * 4;
            f32x4 v = *reinterpret_cast<const f32x4*>(h0d + b * U + j * 32 + ch);
            unsigned h0b, l0b, h1b, l1b, h2b, l2b, h3b, l3b;
            split2(v.x, h0b, l0b); split2(v.y, h1b, l1b);
            split2(v.z, h2b, l2b); split2(v.w, h3b, l3b);
            union { unsigned long long u; unsigned w[2]; } ph, pl;
            ph.w[0] = h0b | (h1b << 16); ph.w[1] = h2b | (h3b << 16);
            pl.w[0] = l0b | (l1b << 16); pl.w[1] = l2b | (l3b << 16);
            *reinterpret_cast<unsigned long long*>(&h_lds[0][0][b][j * 32 + ch]) = ph.u;
            *reinterpret_cast<unsigned long long*>(&h_lds[0][1][b][j * 32 + ch]) = pl.u;
          }
        } else {
          while (__hip_atomic_load(flg + j, __ATOMIC_RELAXED,
                                   __HIP_MEMORY_SCOPE_AGENT) < s)
            __builtin_amdgcn_s_sleep(1);
#pragma unroll
          for (int i = 0; i < 4; ++i) {
            const int c = i * 64 + lane, b = c >> 3, ch = (c & 7) * 4;
            unsigned long long vh = __hip_atomic_load(
                (const unsigned long long*)(hsh + b * U + j * 32 + ch),
                __ATOMIC_RELAXED, __HIP_MEMORY_SCOPE_AGENT);
            unsigned long long vl = __hip_atomic_load(
                (const unsigned long long*)(hsl + b * U + j * 32 + ch),
                __ATOMIC_RELAXED, __HIP_MEMORY_SCOPE_AGENT);
            *reinterpret_cast<unsigned long long*>(&h_lds[par][0][b][j * 32 + ch]) = vh;
            *reinterpret_cast<unsigned long long*>(&h_lds[par][1][b][j * 32 + ch]) = vl;
          }
        }
        __hip_atomic_store(&ld_ready[j], s + 1, __ATOMIC_RELEASE,
                           __HIP_MEMORY_SCOPE_WORKGROUP);
      }
    }
    return;
  }

  // ===================== COMPUTE ROLE (waves 0-7) ==========================
  // MFMA waves 0-5: preload Wh slice (hi+lo) as B-fragments.
  short8 wfh[16], wfl[16];
  float bv = 0.f;
  if (wave < 6) {
    const int g = wave >> 1, half = wave & 1;
    const int c0 = g * 512 + j0 + half * 16;
#pragma unroll
    for (int kk = 0; kk < 16; ++kk) {
      wfh[kk] = *reinterpret_cast<const short8*>(wth + (long)(c0 + lr) * 512 + kk * 32 + kq * 8);
      wfl[kk] = *reinterpret_cast<const short8*>(wtl + (long)(c0 + lr) * 512 + kk * 32 + kq * 8);
    }
    bv = rb[c0 + lr];
  }

  // Register-carried f32 state: thread tid owns task (b = tid>>4, jr pair).
  const int gb = tid >> 4, gjr = (tid & 15) * 2;
  float hpr[2];
  hpr[0] = h0d[gb * U + j0 + gjr];
  hpr[1] = h0d[gb * U + j0 + gjr + 1];

  // xg prefetch
  f32x2 xv[3];
  auto load_xv = [&](int t_in) {
    const long xbase = (long)t_in * 32 * NG;
#pragma unroll
    for (int gg = 0; gg < 3; ++gg)
      xv[gg] = *reinterpret_cast<const f32x2*>(
          xg + xbase + (long)gb * NG + gg * 512 + j0 + gjr);
  };
  load_xv(dir ? (T - 1) : 0);

  for (int s = 0; s < T; ++s) {
    const int par = s & 1;

    // ---- MFMA phase: consume slices as they become ready ----
    if (wave < 6) {
      f32x4 acc0 = {0.f, 0.f, 0.f, 0.f}, acc1 = {0.f, 0.f, 0.f, 0.f};
#pragma unroll
      for (int kk = 0; kk < 16; ++kk) {
        while (__hip_atomic_load(&ld_ready[kk], __ATOMIC_ACQUIRE,
                                 __HIP_MEMORY_SCOPE_WORKGROUP) < s + 1) {
        }
        const short8 a0h = *reinterpret_cast<const short8*>(&h_lds[par][0][lr][kk * 32 + kq * 8]);
        const short8 a0l = *reinterpret_cast<const short8*>(&h_lds[par][1][lr][kk * 32 + kq * 8]);
        const short8 a1h = *reinterpret_cast<const short8*>(&h_lds[par][0][16 + lr][kk * 32 + kq * 8]);
        const short8 a1l = *reinterpret_cast<const short8*>(&h_lds[par][1][16 + lr][kk * 32 + kq * 8]);
        acc0 = mfma16(a0h, wfh[kk], acc0);
        acc0 = mfma16(a0h, wfl[kk], acc0);
        acc0 = mfma16(a0l, wfh[kk], acc0);
        acc1 = mfma16(a1h, wfh[kk], acc1);
        acc1 = mfma16(a1h, wfl[kk], acc1);
        acc1 = mfma16(a1l, wfh[kk], acc1);
      }
#pragma unroll
      for (int r = 0; r < 4; ++r) {
        rg_lds[kq * 4 + r][wave * 16 + lr] = acc0[r] + bv;
        rg_lds[16 + kq * 4 + r][wave * 16 + lr] = acc1[r] + bv;
      }
    }
    sync8(&s8cnt[0], 8 * (s + 1));

    // ---- gates + state update (512 threads, 1 task each) ----
    {
      float hn[2];
#pragma unroll
      for (int e = 0; e < 2; ++e) {
        const int j = gjr + e;
        const float xz = xv[0][e], xr = xv[1][e], xh = xv[2][e];
        const float rz = rg_lds[gb][j], rr = rg_lds[gb][32 + j], rh = rg_lds[gb][64 + j];
        const float z = sigmoidf_(xz + rz);
        const float r = sigmoidf_(xr + rr);
        const float hh = tanhf_(xh + r * rh);
        hn[e] = z * hpr[e] + (1.f - z) * hh;
      }
      hpr[0] = hn[0];
      hpr[1] = hn[1];
      unsigned hi0, lo0, hi1, lo1;
      split2(hn[0], hi0, lo0); split2(hn[1], hi1, lo1);
      unsigned* hdh = (unsigned*)(hbhd + (1 - par) * BU);
      unsigned* hdl = (unsigned*)(hbld + (1 - par) * BU);
      __hip_atomic_store(hdh + (gb * U + j0 + gjr) / 2, hi0 | (hi1 << 16),
                         __ATOMIC_RELAXED, __HIP_MEMORY_SCOPE_AGENT);
      __hip_atomic_store(hdl + (gb * U + j0 + gjr) / 2, lo0 | (lo1 << 16),
                         __ATOMIC_RELAXED, __HIP_MEMORY_SCOPE_AGENT);
      if (layer == 0) {
        const float o0 = hn[0] * SCALE_BN, o1 = hn[1] * SCALE_BN;
        unsigned oh0, ol0, oh1, ol1;
        split2(o0, oh0, ol0); split2(o1, oh1, ol1);
        const long oidx = (((long)s * 32 + gb) * 1024 + dir * 512 + j0 + gjr) >> 1;
        ((unsigned*)out0h)[oidx] = oh0 | (oh1 << 16);
        ((unsigned*)out0l)[oidx] = ol0 | (ol1 << 16);
      } else {
        float* o = outF + ((long)gb * T + s) * 1024 + dir * 512 + j0 + gjr;
        o[0] = hn[0] * SCALE_BN;
        o[1] = hn[1] * SCALE_BN;
      }
      if (s == T - 1) {
        float* o = hT + dir * BU + gb * U + j0 + gjr;
        o[0] = hn[0] * SCALE_BN;
        o[1] = hn[1] * SCALE_BN;
      }
    }
    // Drain own sc1 stores, then 8-wave barrier => all WG stores LLC-visible.
    asm volatile("s_waitcnt vmcnt(0)" ::: "memory");
    sync8(&s8cnt[1], 8 * (s + 1));
    if (tid == 0)
      __hip_atomic_store(flg + wg, s + 1, __ATOMIC_RELAXED, __HIP_MEMORY_SCOPE_AGENT);
    if (s < T - 1) load_xv(dir ? (T - 2 - s) : (s + 1));
  }
}

extern "C" void kernel_launch(void* const* d_in, const int* in_sizes, int n_in,
                              void* d_out, int out_size, void* d_ws, size_t ws_size,
                              hipStream_t stream) {
  (void)in_sizes; (void)n_in; (void)out_size; (void)ws_size;
  const int*   x    = (const int*)d_in[0];
  const float* h0   = (const float*)d_in[1];
  const float* E    = (const float*)d_in[2];
  const float* Wx0f = (const float*)d_in[3];
  const float* Wh0f = (const float*)d_in[4];
  const float* b0f  = (const float*)d_in[5];
  const float* Wx0b = (const float*)d_in[6];
  const float* Wh0b = (const float*)d_in[7];
  const float* b0b  = (const float*)d_in[8];
  const float* Wx1f = (const float*)d_in[9];
  const float* Wh1f = (const float*)d_in[10];
  const float* b1f  = (const float*)d_in[11];
  const float* Wx1b = (const float*)d_in[12];
  const float* Wh1b = (const float*)d_in[13];
  const float* b1b  = (const float*)d_in[14];
  float* dout = (float*)d_out;

  char* p = (char*)d_ws;
  auto alloc = [&p](long bytes) { char* r = p; p += (bytes + 255) & ~255L; return r; };
  float* XGF = (float*)alloc(50331648);            // [8192][1536] f32
  float* XGB = (float*)alloc(50331648);
  unsigned short* OUT0H = (unsigned short*)alloc(16777216);  // [8192][1024] bf16
  unsigned short* OUT0L = (unsigned short*)alloc(16777216);
  unsigned short* X0H = OUT0H;  // alias: X0 dead before OUT0 written
  unsigned short* X0L = OUT0L;
  unsigned short* WHT0FH = (unsigned short*)alloc(1572864);
  unsigned short* WHT0FL = (unsigned short*)alloc(1572864);
  unsigned short* WHT0BH = (unsigned short*)alloc(1572864);
  unsigned short* WHT0BL = (unsigned short*)alloc(1572864);
  unsigned short* WHT1FH = (unsigned short*)alloc(1572864);
  unsigned short* WHT1FL = (unsigned short*)alloc(1572864);
  unsigned short* WHT1BH = (unsigned short*)alloc(1572864);
  unsigned short* WHT1BL = (unsigned short*)alloc(1572864);
  unsigned short* WXT0FH = (unsigned short*)alloc(1572864);
  unsigned short* WXT0FL = (unsigned short*)alloc(1572864);
  unsigned short* WXT0BH = (unsigned short*)alloc(1572864);
  unsigned short* WXT0BL = (unsigned short*)alloc(1572864);
  unsigned short* WXT1FH = (unsigned short*)alloc(3145728);
  unsigned short* WXT1FL = (unsigned short*)alloc(3145728);
  unsigned short* WXT1BH = (unsigned short*)alloc(3145728);
  unsigned short* WXT1BL = (unsigned short*)alloc(3145728);
  unsigned short* HBH = (unsigned short*)alloc(131072);  // [2][2][BU] bf16
  unsigned short* HBL = (unsigned short*)alloc(131072);
  int* FLAGS = (int*)alloc(256);

  hipMemsetAsync(FLAGS, 0, 256, stream);

  dim3 blk(256);
  transpose_w<<<dim3(48, 16), blk, 0, stream>>>(Wh0f, WHT0FH, WHT0FL, 512, NG);
  transpose_w<<<dim3(48, 16), blk, 0, stream>>>(Wh0b, WHT0BH, WHT0BL, 512, NG);
  transpose_w<<<dim3(48, 16), blk, 0, stream>>>(Wh1f, WHT1FH, WHT1FL, 512, NG);
  transpose_w<<<dim3(48, 16), blk, 0, stream>>>(Wh1b, WHT1BH, WHT1BL, 512, NG);
  transpose_w<<<dim3(48, 16), blk, 0, stream>>>(Wx0f, WXT0FH, WXT0FL, 512, NG);
  transpose_w<<<dim3(48, 16), blk, 0, stream>>>(Wx0b, WXT0BH, WXT0BL, 512, NG);
  transpose_w<<<dim3(48, 32), blk, 0, stream>>>(Wx1f, WXT1FH, WXT1FL, 1024, NG);
  transpose_w<<<dim3(48, 32), blk, 0, stream>>>(Wx1b, WXT1BH, WXT1BL, 1024, NG);

  embed_kernel<<<dim3(8192), blk, 0, stream>>>(x, E, X0H, X0L);

  // layer 0
  gemm_bias<512><<<dim3(64, 12), blk, 0, stream>>>(
      X0H, X0L, WXT0FH, WXT0FL, b0f, XGF);
  gemm_bias<512><<<dim3(64, 12), blk, 0, stream>>>(
      X0H, X0L, WXT0BH, WXT0BL, b0b, XGB);
  gru_scan<<<dim3(32), dim3(768), 0, stream>>>(
      XGF, XGB, WHT0FH, WHT0FL, WHT0BH, WHT0BL, b0f + NG, b0b + NG, h0,
      HBH, HBL, FLAGS, OUT0H, OUT0L, nullptr, dout + OUT_ELEMS, 0);

  // layer 1
  gemm_bias<1024><<<dim3(64, 12), blk, 0, stream>>>(
      OUT0H, OUT0L, WXT1FH, WXT1FL, b1f, XGF);
  gemm_bias<1024><<<dim3(64, 12), blk, 0, stream>>>(
      OUT0H, OUT0L, WXT1BH, WXT1BL, b1b, XGB);
  gru_scan<<<dim3(32), dim3(768), 0, stream>>>(
      XGF, XGB, WHT1FH, WHT1FL, WHT1BH, WHT1BL, b1f + NG, b1b + NG, h0 + 2 * BU,
      HBH, HBL, FLAGS + 32, nullptr, nullptr, dout, dout + OUT_ELEMS + 2 * BU, 1);
}